// Round 1
// baseline (670.102 us; speedup 1.0000x reference)
//
#include <hip/hip_runtime.h>
#include <hip/hip_bf16.h>

#define HID 1024
#define NHEAD 16
#define HDIM 64
#define BB 4
#define SS 2048
#define MTOK (BB * SS)   // 8192 tokens

typedef __attribute__((ext_vector_type(8))) short bf16x8;
typedef __attribute__((ext_vector_type(4))) float f32x4;

__device__ __forceinline__ unsigned short f2bs(float f) {
  __hip_bfloat16 h = __float2bfloat16(f);
  unsigned short u;
  __builtin_memcpy(&u, &h, 2);
  return u;
}

// ---- stage a 128x32 bf16 tile into LDS from fp32 global (converting) ----
__device__ __forceinline__ void stage_tile(unsigned short* s, const float* g, int ldg, int tid) {
#pragma unroll
  for (int i = 0; i < 4; i++) {
    int c = i * 256 + tid;       // float4 chunk id (4 elems each), 1024 total
    int row = c >> 3;            // 8 chunks per 32-elem row
    int col = (c & 7) * 4;
    const float4 v = *(const float4*)(g + (size_t)row * ldg + col);
    ushort4 hv;
    hv.x = f2bs(v.x); hv.y = f2bs(v.y); hv.z = f2bs(v.z); hv.w = f2bs(v.w);
    *(ushort4*)(s + c * 4) = hv;
  }
}
// ---- stage a 128x32 bf16 tile into LDS from bf16 global ----
__device__ __forceinline__ void stage_tile(unsigned short* s, const unsigned short* g, int ldg, int tid) {
#pragma unroll
  for (int i = 0; i < 2; i++) {
    int c = i * 256 + tid;       // 8-elem (16B) chunk id, 512 total
    int row = c >> 2;            // 4 chunks per 32-elem row
    int col = (c & 3) * 8;
    const uint4 v = *(const uint4*)(g + (size_t)row * ldg + col);
    *(uint4*)(s + c * 8) = v;
  }
}

__device__ __forceinline__ void store_c(float* p, float v) { *p = v; }
__device__ __forceinline__ void store_c(unsigned short* p, float v) { *p = f2bs(v); }

// C[M,N] = A[M,K] @ W[N,K]^T + bias[N]
// 128x128 block tile, 4 waves in 2x2, each wave 64x64 via 4x4 of 16x16x32 MFMA.
template <typename TA, typename TC>
__global__ __launch_bounds__(256) void gemm_bt(const TA* __restrict__ A, const float* __restrict__ W,
                                               const float* __restrict__ bias, TC* __restrict__ C,
                                               int M, int N, int K) {
  __shared__ unsigned short As[128 * 32];
  __shared__ unsigned short Bs[128 * 32];
  const int nb = N >> 7;
  const int m0 = (blockIdx.x / nb) << 7;
  const int n0 = (blockIdx.x % nb) << 7;
  const int tid = threadIdx.x;
  const int lane = tid & 63, wave = tid >> 6;
  const int quad = lane >> 4, l15 = lane & 15;
  const int wm = ((wave >> 1) << 6), wn = ((wave & 1) << 6);

  f32x4 acc[4][4] = {};

  for (int k0 = 0; k0 < K; k0 += 32) {
    __syncthreads();  // previous iteration's LDS reads complete
    stage_tile(As, A + (size_t)m0 * K + k0, K, tid);
    stage_tile(Bs, W + (size_t)n0 * K + k0, K, tid);
    __syncthreads();
    bf16x8 af[4], bfr[4];
#pragma unroll
    for (int i = 0; i < 4; i++)
      af[i] = *(const bf16x8*)(As + (wm + i * 16 + l15) * 32 + quad * 8);
#pragma unroll
    for (int j = 0; j < 4; j++)
      bfr[j] = *(const bf16x8*)(Bs + (wn + j * 16 + l15) * 32 + quad * 8);
#pragma unroll
    for (int i = 0; i < 4; i++)
#pragma unroll
      for (int j = 0; j < 4; j++)
        acc[i][j] = __builtin_amdgcn_mfma_f32_16x16x32_bf16(af[i], bfr[j], acc[i][j], 0, 0, 0);
  }

#pragma unroll
  for (int j = 0; j < 4; j++) {
    const int col = n0 + wn + j * 16 + l15;
    const float bv = bias[col];
#pragma unroll
    for (int i = 0; i < 4; i++) {
      const int row = m0 + wm + i * 16 + quad * 4;
#pragma unroll
      for (int r = 0; r < 4; r++)
        store_c(C + (size_t)(row + r) * N + col, acc[i][j][r] + bv);
    }
  }
}

// Flash attention: one block per (b, h, 64-row Q tile). 4 waves; wave w owns 16 Q rows.
// q/k/v stored bf16 as [B*S, H] (head h occupies cols h*64..h*64+63).
__global__ __launch_bounds__(256) void attn_kernel(const unsigned short* __restrict__ qp,
                                                   const unsigned short* __restrict__ kp,
                                                   const unsigned short* __restrict__ vp,
                                                   const float* __restrict__ mask,
                                                   unsigned short* __restrict__ ctx) {
  __shared__ unsigned short Ks[64 * 72];        // K tile  [kv_row][d], stride 72 (pad)
  __shared__ unsigned short Vt[64 * 72];        // V^T tile [d][kv_row], stride 72 (pad)
  __shared__ unsigned short Ps[4 * 16 * 72];    // per-wave P tile [q_row][kv_col], stride 72

  const int bid = blockIdx.x;
  const int qt = bid & 31;            // S/64 = 32 Q tiles
  const int h  = (bid >> 5) & 15;
  const int b  = bid >> 9;
  const int tid = threadIdx.x;
  const int wave = tid >> 6, lane = tid & 63;
  const int quad = lane >> 4, l15 = lane & 15;
  const int q0 = qt * 64 + wave * 16;

  // Q fragments live in registers for the whole kernel
  const unsigned short* qbase = qp + ((size_t)(b * SS) + q0 + l15) * HID + h * 64;
  bf16x8 qf[2];
  qf[0] = *(const bf16x8*)(qbase + quad * 8);
  qf[1] = *(const bf16x8*)(qbase + 32 + quad * 8);

  f32x4 O[4] = {};
  float mrun[4], lrun[4];
#pragma unroll
  for (int r = 0; r < 4; r++) { mrun[r] = -1e30f; lrun[r] = 0.0f; }

  for (int kb = 0; kb < SS / 64; kb++) {
    __syncthreads();  // previous iteration's Ks/Vt reads complete
    {
      const unsigned short* kg = kp + ((size_t)(b * SS) + kb * 64) * HID + h * 64;
      const unsigned short* vg = vp + ((size_t)(b * SS) + kb * 64) * HID + h * 64;
#pragma unroll
      for (int i = 0; i < 2; i++) {
        int c = i * 256 + tid;       // 512 chunks of 8 elems
        int row = c >> 3;            // 8 chunks per 64-elem row
        int col = (c & 7) * 8;
        uint4 v = *(const uint4*)(kg + (size_t)row * HID + col);
        *(uint4*)(&Ks[row * 72 + col]) = v;
      }
#pragma unroll
      for (int i = 0; i < 2; i++) {
        int c = i * 256 + tid;
        int row = c >> 3;
        int col = (c & 7) * 8;
        uint4 v = *(const uint4*)(vg + (size_t)row * HID + col);
        unsigned short tmp[8];
        *(uint4*)tmp = v;
#pragma unroll
        for (int j = 0; j < 8; j++) Vt[(col + j) * 72 + row] = tmp[j];
      }
    }
    __syncthreads();

    // S = Q K^T  (16 q rows x 64 kv cols per wave)
    f32x4 Sc[4] = {};
#pragma unroll
    for (int nt = 0; nt < 4; nt++) {
#pragma unroll
      for (int kc = 0; kc < 2; kc++) {
        bf16x8 kf = *(const bf16x8*)(&Ks[(nt * 16 + l15) * 72 + kc * 32 + quad * 8]);
        Sc[nt] = __builtin_amdgcn_mfma_f32_16x16x32_bf16(qf[kc], kf, Sc[nt], 0, 0, 0);
      }
    }

    // scale + mask
    float madd[4];
#pragma unroll
    for (int nt = 0; nt < 4; nt++) {
      float mv = mask[b * SS + kb * 64 + nt * 16 + l15];
      madd[nt] = (1.0f - mv) * -10000.0f;
    }
#pragma unroll
    for (int nt = 0; nt < 4; nt++)
#pragma unroll
      for (int r = 0; r < 4; r++)
        Sc[nt][r] = Sc[nt][r] * 0.125f + madd[nt];

    // online softmax (rows are quad*4+r; reduce across l15 lanes)
#pragma unroll
    for (int r = 0; r < 4; r++) {
      float mx = fmaxf(fmaxf(Sc[0][r], Sc[1][r]), fmaxf(Sc[2][r], Sc[3][r]));
#pragma unroll
      for (int off = 1; off < 16; off <<= 1) mx = fmaxf(mx, __shfl_xor(mx, off));
      float mnew = fmaxf(mrun[r], mx);
      float alpha = __expf(mrun[r] - mnew);
      mrun[r] = mnew;
      float rs = 0.0f;
#pragma unroll
      for (int nt = 0; nt < 4; nt++) {
        float p = __expf(Sc[nt][r] - mnew);
        Sc[nt][r] = p;
        rs += p;
      }
#pragma unroll
      for (int off = 1; off < 16; off <<= 1) rs += __shfl_xor(rs, off);
      lrun[r] = lrun[r] * alpha + rs;
#pragma unroll
      for (int t = 0; t < 4; t++) O[t][r] *= alpha;
    }

    // P -> LDS (C-layout out, A-layout back in)
    unsigned short* pw = &Ps[wave * 16 * 72];
#pragma unroll
    for (int nt = 0; nt < 4; nt++)
#pragma unroll
      for (int r = 0; r < 4; r++)
        pw[(quad * 4 + r) * 72 + nt * 16 + l15] = f2bs(Sc[nt][r]);
    __syncthreads();

    // O += P V
#pragma unroll
    for (int kc = 0; kc < 2; kc++) {
      bf16x8 pf = *(const bf16x8*)(&pw[l15 * 72 + kc * 32 + quad * 8]);
#pragma unroll
      for (int t = 0; t < 4; t++) {
        bf16x8 vf = *(const bf16x8*)(&Vt[(t * 16 + l15) * 72 + kc * 32 + quad * 8]);
        O[t] = __builtin_amdgcn_mfma_f32_16x16x32_bf16(pf, vf, O[t], 0, 0, 0);
      }
    }
  }

  // normalize + write ctx (bf16, [B*S, H] layout)
#pragma unroll
  for (int r = 0; r < 4; r++) {
    float inv = 1.0f / lrun[r];
    size_t row = (size_t)(b * SS) + q0 + quad * 4 + r;
#pragma unroll
    for (int t = 0; t < 4; t++)
      ctx[row * HID + h * 64 + t * 16 + l15] = f2bs(O[t][r] * inv);
  }
}

extern "C" void kernel_launch(void* const* d_in, const int* in_sizes, int n_in,
                              void* d_out, int out_size, void* d_ws, size_t ws_size,
                              hipStream_t stream) {
  const float* query = (const float*)d_in[0];
  const float* key_  = (const float*)d_in[1];
  const float* value = (const float*)d_in[2];
  const float* mask  = (const float*)d_in[3];
  const float* Wq = (const float*)d_in[4];
  const float* bq = (const float*)d_in[5];
  const float* Wk = (const float*)d_in[6];
  const float* bk = (const float*)d_in[7];
  const float* Wv = (const float*)d_in[8];
  const float* bv = (const float*)d_in[9];
  const float* Wo = (const float*)d_in[10];
  const float* bo = (const float*)d_in[11];
  float* out = (float*)d_out;

  unsigned short* qp = (unsigned short*)d_ws;                // 16 MB each, bf16
  unsigned short* kp = qp + (size_t)MTOK * HID;
  unsigned short* vp = kp + (size_t)MTOK * HID;
  unsigned short* cx = vp + (size_t)MTOK * HID;

  dim3 blk(256);
  const int gblocks = (MTOK / 128) * (HID / 128);  // 512

  gemm_bt<float, unsigned short><<<gblocks, blk, 0, stream>>>(query, Wq, bq, qp, MTOK, HID, HID);
  gemm_bt<float, unsigned short><<<gblocks, blk, 0, stream>>>(key_, Wk, bk, kp, MTOK, HID, HID);
  gemm_bt<float, unsigned short><<<gblocks, blk, 0, stream>>>(value, Wv, bv, vp, MTOK, HID, HID);

  attn_kernel<<<BB * NHEAD * (SS / 64), blk, 0, stream>>>(qp, kp, vp, mask, cx);

  gemm_bt<unsigned short, float><<<gblocks, blk, 0, stream>>>(cx, Wo, bo, out, MTOK, HID, HID);
}

// Round 2
// 502.260 us; speedup vs baseline: 1.3342x; 1.3342x over previous
//
#include <hip/hip_runtime.h>
#include <hip/hip_bf16.h>

#define HID 1024
#define NHEAD 16
#define HDIM 64
#define BB 4
#define SS 2048
#define MTOK (BB * SS)   // 8192 tokens

typedef __attribute__((ext_vector_type(8))) short bf16x8;
typedef __attribute__((ext_vector_type(4))) float f32x4;

__device__ __forceinline__ unsigned short f2bs(float f) {
  __hip_bfloat16 h = __float2bfloat16(f);
  unsigned short u;
  __builtin_memcpy(&u, &h, 2);
  return u;
}

// ---- stage a 128x32 bf16 tile into LDS from fp32 global (converting) ----
__device__ __forceinline__ void stage_tile(unsigned short* s, const float* g, int ldg, int tid) {
#pragma unroll
  for (int i = 0; i < 4; i++) {
    int c = i * 256 + tid;       // float4 chunk id (4 elems each), 1024 total
    int row = c >> 3;            // 8 chunks per 32-elem row
    int col = (c & 7) * 4;
    const float4 v = *(const float4*)(g + (size_t)row * ldg + col);
    ushort4 hv;
    hv.x = f2bs(v.x); hv.y = f2bs(v.y); hv.z = f2bs(v.z); hv.w = f2bs(v.w);
    *(ushort4*)(s + c * 4) = hv;
  }
}
// ---- stage a 128x32 bf16 tile into LDS from bf16 global ----
__device__ __forceinline__ void stage_tile(unsigned short* s, const unsigned short* g, int ldg, int tid) {
#pragma unroll
  for (int i = 0; i < 2; i++) {
    int c = i * 256 + tid;       // 8-elem (16B) chunk id, 512 total
    int row = c >> 2;            // 4 chunks per 32-elem row
    int col = (c & 3) * 8;
    const uint4 v = *(const uint4*)(g + (size_t)row * ldg + col);
    *(uint4*)(s + c * 8) = v;
  }
}

// C[M,N] = A[M,K] @ W[N,K]^T + bias[N]
// 128x128 block tile, 4 waves in 2x2, each wave 64x64 via 4x4 of 16x16x32 MFMA.
// MODE 0: fp32 out, token-major [M,N]
// MODE 1: bf16 out, head-major [B,NH,S,HD]
// MODE 2: bf16 out, head-major transposed [B,NH,HD,S]
template <typename TA, int MODE>
__global__ __launch_bounds__(256) void gemm_bt(const TA* __restrict__ A, const float* __restrict__ W,
                                               const float* __restrict__ bias, void* __restrict__ Cp,
                                               int M, int N, int K) {
  __shared__ unsigned short As[128 * 32];
  __shared__ unsigned short Bs[128 * 32];
  const int nb = N >> 7;
  const int m0 = (blockIdx.x / nb) << 7;
  const int n0 = (blockIdx.x % nb) << 7;
  const int tid = threadIdx.x;
  const int lane = tid & 63, wave = tid >> 6;
  const int quad = lane >> 4, l15 = lane & 15;
  const int wm = ((wave >> 1) << 6), wn = ((wave & 1) << 6);

  f32x4 acc[4][4] = {};

  for (int k0 = 0; k0 < K; k0 += 32) {
    __syncthreads();  // previous iteration's LDS reads complete
    stage_tile(As, A + (size_t)m0 * K + k0, K, tid);
    stage_tile(Bs, W + (size_t)n0 * K + k0, K, tid);
    __syncthreads();
    bf16x8 af[4], bfr[4];
#pragma unroll
    for (int i = 0; i < 4; i++)
      af[i] = *(const bf16x8*)(As + (wm + i * 16 + l15) * 32 + quad * 8);
#pragma unroll
    for (int j = 0; j < 4; j++)
      bfr[j] = *(const bf16x8*)(Bs + (wn + j * 16 + l15) * 32 + quad * 8);
#pragma unroll
    for (int i = 0; i < 4; i++)
#pragma unroll
      for (int j = 0; j < 4; j++)
        acc[i][j] = __builtin_amdgcn_mfma_f32_16x16x32_bf16(af[i], bfr[j], acc[i][j], 0, 0, 0);
  }

#pragma unroll
  for (int j = 0; j < 4; j++) {
    const int col = n0 + wn + j * 16 + l15;
    const float bv = bias[col];
    if constexpr (MODE == 0) {
      float* outp = (float*)Cp;
#pragma unroll
      for (int i = 0; i < 4; i++) {
        const int row0 = m0 + wm + i * 16 + quad * 4;
#pragma unroll
        for (int r = 0; r < 4; r++)
          outp[(size_t)(row0 + r) * N + col] = acc[i][j][r] + bv;
      }
    } else if constexpr (MODE == 1) {
      unsigned short* outp = (unsigned short*)Cp;
      const int hh = col >> 6, d = col & 63;
#pragma unroll
      for (int i = 0; i < 4; i++) {
        const int row0 = m0 + wm + i * 16 + quad * 4;
        const int bb = row0 >> 11, s0 = row0 & 2047;
        const size_t base = ((size_t)(bb * NHEAD + hh)) * SS * HDIM + (size_t)s0 * HDIM + d;
#pragma unroll
        for (int r = 0; r < 4; r++)
          outp[base + (size_t)r * HDIM] = f2bs(acc[i][j][r] + bv);
      }
    } else {
      unsigned short* outp = (unsigned short*)Cp;
      const int hh = col >> 6, d = col & 63;
#pragma unroll
      for (int i = 0; i < 4; i++) {
        const int row0 = m0 + wm + i * 16 + quad * 4;
        const int bb = row0 >> 11, s0 = row0 & 2047;
        ushort4 pk;
        pk.x = f2bs(acc[i][j][0] + bv);
        pk.y = f2bs(acc[i][j][1] + bv);
        pk.z = f2bs(acc[i][j][2] + bv);
        pk.w = f2bs(acc[i][j][3] + bv);
        *(ushort4*)&outp[((size_t)(bb * NHEAD + hh)) * HDIM * SS + (size_t)d * SS + s0] = pk;
      }
    }
  }
}

// Flash attention v2: one block per (b, h, 64-row Q tile); 4 waves, wave owns 16 q rows.
// Computes S^T = K Q^T so softmax reductions are mostly in-register and the
// P->LDS round trip is contiguous ushort4 writes. KV tile = 128.
// q,k head-major [B,NH,S,64]; vt transposed [B,NH,64,S]; ctx token-major [B*S,H] bf16.
#define KSTR 72
#define VSTR 136
#define PSTR 136

__global__ __launch_bounds__(256) void attn_v2(const unsigned short* __restrict__ q,
                                               const unsigned short* __restrict__ k,
                                               const unsigned short* __restrict__ vt,
                                               const float* __restrict__ mask,
                                               unsigned short* __restrict__ ctx) {
  __shared__ unsigned short Ks[128 * KSTR];
  __shared__ unsigned short Vts[64 * VSTR];
  __shared__ unsigned short Ps[4 * 16 * PSTR];
  __shared__ float Ms[128];

  const int bid = blockIdx.x;
  const int qt = bid & 31;
  const int h  = (bid >> 5) & 15;
  const int b  = bid >> 9;
  const int bh = b * NHEAD + h;
  const int tid = threadIdx.x;
  const int wave = tid >> 6, lane = tid & 63;
  const int quad = lane >> 4, l15 = lane & 15;
  const int q0 = qt * 64 + wave * 16;

  // Q fragments (B operand of S^T): lane reads q row q0+l15, 16B chunks
  const unsigned short* qbase = q + ((size_t)bh * SS + q0 + l15) * HDIM;
  bf16x8 qf[2];
  qf[0] = *(const bf16x8*)(qbase + quad * 8);
  qf[1] = *(const bf16x8*)(qbase + 32 + quad * 8);

  f32x4 O[4] = {};
  float mrun = -1e30f, lrun = 0.0f;

  const unsigned short* kg0 = k + (size_t)bh * SS * HDIM;
  const unsigned short* vg0 = vt + (size_t)bh * HDIM * SS;
  unsigned short* pw = &Ps[wave * 16 * PSTR];

  for (int kb = 0; kb < SS / 128; kb++) {
    __syncthreads();  // previous iteration's Ks/Vts reads complete
    {
      // K tile: 128 kv rows x 64 d — fully contiguous 16 KB
      const unsigned short* kg = kg0 + (size_t)kb * 128 * HDIM;
#pragma unroll
      for (int i = 0; i < 4; i++) {
        int c = i * 256 + tid;        // 1024 chunks of 8 elems
        uint4 vv = *(const uint4*)(kg + c * 8);
        int row = c >> 3, col = (c & 7) * 8;
        *(uint4*)&Ks[row * KSTR + col] = vv;
      }
      // Vt tile: 64 d rows x 128 kv, global row stride SS
      const unsigned short* vg = vg0 + (size_t)kb * 128;
#pragma unroll
      for (int i = 0; i < 4; i++) {
        int c = i * 256 + tid;
        int row = c >> 4, col = (c & 15) * 8;
        uint4 vv = *(const uint4*)(vg + (size_t)row * SS + col);
        *(uint4*)&Vts[row * VSTR + col] = vv;
      }
      if (tid < 128) Ms[tid] = (1.0f - mask[b * SS + kb * 128 + tid]) * -10000.0f;
    }
    __syncthreads();

    // S^T = K Q^T : C layout col=l15 (q), row=quad*4+r (kv within mt tile)
    f32x4 Sc[8];
#pragma unroll
    for (int mt = 0; mt < 8; mt++) {
      f32x4 z = {};
#pragma unroll
      for (int kc = 0; kc < 2; kc++) {
        bf16x8 kf = *(const bf16x8*)&Ks[(mt * 16 + l15) * KSTR + kc * 32 + quad * 8];
        z = __builtin_amdgcn_mfma_f32_16x16x32_bf16(kf, qf[kc], z, 0, 0, 0);
      }
      f32x4 mv = *(const f32x4*)&Ms[mt * 16 + quad * 4];
      Sc[mt] = z * 0.125f + mv;
    }

    // online softmax: lane owns q=l15 column; kv spread over regs + 4 quads
    float mx = -1e30f;
#pragma unroll
    for (int mt = 0; mt < 8; mt++)
#pragma unroll
      for (int r = 0; r < 4; r++) mx = fmaxf(mx, Sc[mt][r]);
    mx = fmaxf(mx, __shfl_xor(mx, 16));
    mx = fmaxf(mx, __shfl_xor(mx, 32));
    float mnew = fmaxf(mrun, mx);
    float alpha = __expf(mrun - mnew);
    mrun = mnew;
    float rs = 0.0f;
#pragma unroll
    for (int mt = 0; mt < 8; mt++)
#pragma unroll
      for (int r = 0; r < 4; r++) {
        float p = __expf(Sc[mt][r] - mnew);
        Sc[mt][r] = p;
        rs += p;
      }
    rs += __shfl_xor(rs, 16);
    rs += __shfl_xor(rs, 32);
    lrun = lrun * alpha + rs;

    // broadcast alpha to O's row layout (row q' = quad*4+r lives in lane l15=q')
    float al[4];
#pragma unroll
    for (int r = 0; r < 4; r++) al[r] = __shfl(alpha, quad * 4 + r);
#pragma unroll
    for (int nt = 0; nt < 4; nt++)
#pragma unroll
      for (int r = 0; r < 4; r++) O[nt][r] *= al[r];

    // P rows [q=l15][kv 0..127]: contiguous ushort4 per mt (per-wave region, no barrier)
#pragma unroll
    for (int mt = 0; mt < 8; mt++) {
      ushort4 pk;
      pk.x = f2bs(Sc[mt][0]); pk.y = f2bs(Sc[mt][1]);
      pk.z = f2bs(Sc[mt][2]); pk.w = f2bs(Sc[mt][3]);
      *(ushort4*)&pw[l15 * PSTR + mt * 16 + quad * 4] = pk;
    }

    // O += P V  (A = P from pw rows, B = V^T from Vts rows)
#pragma unroll
    for (int kc = 0; kc < 4; kc++) {
      bf16x8 pf = *(const bf16x8*)&pw[l15 * PSTR + kc * 32 + quad * 8];
#pragma unroll
      for (int nt = 0; nt < 4; nt++) {
        bf16x8 vf = *(const bf16x8*)&Vts[(nt * 16 + l15) * VSTR + kc * 32 + quad * 8];
        O[nt] = __builtin_amdgcn_mfma_f32_16x16x32_bf16(pf, vf, O[nt], 0, 0, 0);
      }
    }
  }

  // normalize + write ctx (token-major bf16)
  float invl = 1.0f / lrun;
  float lr[4];
#pragma unroll
  for (int r = 0; r < 4; r++) lr[r] = __shfl(invl, quad * 4 + r);
#pragma unroll
  for (int nt = 0; nt < 4; nt++)
#pragma unroll
    for (int r = 0; r < 4; r++)
      ctx[((size_t)(b * SS) + q0 + quad * 4 + r) * HID + h * 64 + nt * 16 + l15] =
          f2bs(O[nt][r] * lr[r]);
}

extern "C" void kernel_launch(void* const* d_in, const int* in_sizes, int n_in,
                              void* d_out, int out_size, void* d_ws, size_t ws_size,
                              hipStream_t stream) {
  const float* query = (const float*)d_in[0];
  const float* key_  = (const float*)d_in[1];
  const float* value = (const float*)d_in[2];
  const float* mask  = (const float*)d_in[3];
  const float* Wq = (const float*)d_in[4];
  const float* bq = (const float*)d_in[5];
  const float* Wk = (const float*)d_in[6];
  const float* bk = (const float*)d_in[7];
  const float* Wv = (const float*)d_in[8];
  const float* bv = (const float*)d_in[9];
  const float* Wo = (const float*)d_in[10];
  const float* bo = (const float*)d_in[11];
  float* out = (float*)d_out;

  unsigned short* qhm = (unsigned short*)d_ws;               // [B,NH,S,64] bf16
  unsigned short* khm = qhm + (size_t)MTOK * HID;            // [B,NH,S,64]
  unsigned short* vth = khm + (size_t)MTOK * HID;            // [B,NH,64,S]
  unsigned short* cx  = vth + (size_t)MTOK * HID;            // [B*S,H]

  dim3 blk(256);
  const int gblocks = (MTOK / 128) * (HID / 128);  // 512

  gemm_bt<float, 1><<<gblocks, blk, 0, stream>>>(query, Wq, bq, qhm, MTOK, HID, HID);
  gemm_bt<float, 1><<<gblocks, blk, 0, stream>>>(key_, Wk, bk, khm, MTOK, HID, HID);
  gemm_bt<float, 2><<<gblocks, blk, 0, stream>>>(value, Wv, bv, vth, MTOK, HID, HID);

  attn_v2<<<BB * NHEAD * (SS / 64), blk, 0, stream>>>(qhm, khm, vth, mask, cx);

  gemm_bt<unsigned short, 0><<<gblocks, blk, 0, stream>>>(cx, Wo, bo, out, MTOK, HID, HID);
}

// Round 3
// 427.241 us; speedup vs baseline: 1.5684x; 1.1756x over previous
//
#include <hip/hip_runtime.h>
#include <hip/hip_bf16.h>

#define HID 1024
#define NHEAD 16
#define HDIM 64
#define BB 4
#define SS 2048
#define MTOK (BB * SS)   // 8192 tokens

typedef __attribute__((ext_vector_type(8))) short bf16x8;
typedef __attribute__((ext_vector_type(4))) float f32x4;

__device__ __forceinline__ unsigned short f2bs(float f) {
  __hip_bfloat16 h = __float2bfloat16(f);
  unsigned short u;
  __builtin_memcpy(&u, &h, 2);
  return u;
}

// async global->LDS, 16B per lane. LDS dest = wave-uniform base + lane*16.
__device__ __forceinline__ void gload16(const void* g, void* l) {
  __builtin_amdgcn_global_load_lds((__attribute__((address_space(1))) const void*)g,
                                   (__attribute__((address_space(3))) void*)l, 16, 0, 0);
}

// ===================== conversion pass (fp32 -> bf16) =====================
// blocks 0..3071: query/key_/value (1024 blocks each, 8192 elems/block)
// blocks 3072..3583: Wq,Wk,Wv,Wo (128 blocks each)
__global__ __launch_bounds__(256) void cvt_all(
    const float* __restrict__ s_q, const float* __restrict__ s_k, const float* __restrict__ s_v,
    const float* __restrict__ wq, const float* __restrict__ wk, const float* __restrict__ wv,
    const float* __restrict__ wo,
    unsigned short* __restrict__ xq, unsigned short* __restrict__ xk, unsigned short* __restrict__ xv,
    unsigned short* __restrict__ wcat, unsigned short* __restrict__ wobf) {
  const int bid = blockIdx.x;
  const float* src;
  unsigned short* dst;
  size_t off;
  if (bid < 3072) {
    int s = bid >> 10;
    src = (s == 0 ? s_q : (s == 1 ? s_k : s_v));
    dst = (s == 0 ? xq : (s == 1 ? xk : xv));
    off = (size_t)(bid & 1023) * 8192;
  } else {
    int s = (bid - 3072) >> 7;
    src = (s == 0 ? wq : (s == 1 ? wk : (s == 2 ? wv : wo)));
    dst = (s < 3 ? wcat + (size_t)s * HID * HID : wobf);
    off = (size_t)((bid - 3072) & 127) * 8192;
  }
  src += off;
  dst += off;
  const int t = threadIdx.x;
#pragma unroll
  for (int i = 0; i < 8; i++) {
    float4 f = *(const float4*)(src + (size_t)(i * 256 + t) * 4);
    ushort4 h;
    h.x = f2bs(f.x); h.y = f2bs(f.y); h.z = f2bs(f.z); h.w = f2bs(f.w);
    *(ushort4*)(dst + (size_t)(i * 256 + t) * 4) = h;
  }
}

// ===================== fused QKV GEMM (bf16, global_load_lds) =====================
// grid: 64 m-tiles x 24 n-tiles. n-tile 0-7 -> Q (head-major), 8-15 -> K (head-major),
// 16-23 -> V (transposed per head [B,NH,HD,S]).
__global__ __launch_bounds__(256) void qkv_gemm(
    const unsigned short* __restrict__ xq, const unsigned short* __restrict__ xk,
    const unsigned short* __restrict__ xv, const unsigned short* __restrict__ wcat,
    const float* __restrict__ bq, const float* __restrict__ bk, const float* __restrict__ bv,
    unsigned short* __restrict__ qhm, unsigned short* __restrict__ khm,
    unsigned short* __restrict__ vth) {
  __shared__ unsigned short As[128 * 32];
  __shared__ unsigned short Bs[128 * 32];
  const int bid = blockIdx.x;
  const int mt = bid / 24, nt = bid % 24;
  const int sel = nt >> 3;
  const int m0 = mt << 7, n0 = (nt & 7) << 7;
  const int tid = threadIdx.x;
  const int lane = tid & 63, wave = tid >> 6;
  const int quad = lane >> 4, l15 = lane & 15;
  const int wm = ((wave >> 1) << 6), wn = ((wave & 1) << 6);

  const unsigned short* A = (sel == 0 ? xq : (sel == 1 ? xk : xv));
  const unsigned short* W = wcat + (size_t)sel * HID * HID;
  const float* bias = (sel == 0 ? bq : (sel == 1 ? bk : bv));

  // 16B chunk ids: tile = 128 rows x 32 shorts = 512 chunks; 4 chunks/row
  const int c0 = wave * 128 + lane;
  const int c1 = c0 + 64;
  const unsigned short* gA0 = A + (size_t)(m0 + (c0 >> 2)) * HID + (c0 & 3) * 8;
  const unsigned short* gA1 = A + (size_t)(m0 + (c1 >> 2)) * HID + (c1 & 3) * 8;
  const unsigned short* gB0 = W + (size_t)(n0 + (c0 >> 2)) * HID + (c0 & 3) * 8;
  const unsigned short* gB1 = W + (size_t)(n0 + (c1 >> 2)) * HID + (c1 & 3) * 8;
  unsigned short* lA0 = As + (size_t)(wave * 128) * 8;   // wave-uniform
  unsigned short* lA1 = lA0 + 64 * 8;
  unsigned short* lB0 = Bs + (size_t)(wave * 128) * 8;
  unsigned short* lB1 = lB0 + 64 * 8;

  f32x4 acc[4][4] = {};

  for (int k0 = 0; k0 < HID; k0 += 32) {
    __syncthreads();  // previous iteration's ds_reads complete
    gload16(gA0 + k0, lA0);
    gload16(gA1 + k0, lA1);
    gload16(gB0 + k0, lB0);
    gload16(gB1 + k0, lB1);
    __syncthreads();  // drains vmcnt: staged data visible
    bf16x8 af[4], bfr[4];
#pragma unroll
    for (int i = 0; i < 4; i++)
      af[i] = *(const bf16x8*)(As + (wm + i * 16 + l15) * 32 + quad * 8);
#pragma unroll
    for (int j = 0; j < 4; j++)
      bfr[j] = *(const bf16x8*)(Bs + (wn + j * 16 + l15) * 32 + quad * 8);
#pragma unroll
    for (int i = 0; i < 4; i++)
#pragma unroll
      for (int j = 0; j < 4; j++)
        acc[i][j] = __builtin_amdgcn_mfma_f32_16x16x32_bf16(af[i], bfr[j], acc[i][j], 0, 0, 0);
  }

#pragma unroll
  for (int j = 0; j < 4; j++) {
    const int col = n0 + wn + j * 16 + l15;
    const float bvv = bias[col];
    const int hh = col >> 6, d = col & 63;
    if (sel < 2) {
      unsigned short* outp = (sel == 0 ? qhm : khm);
#pragma unroll
      for (int i = 0; i < 4; i++) {
        const int row0 = m0 + wm + i * 16 + quad * 4;
        const int bb = row0 >> 11, s0 = row0 & 2047;
        const size_t base = ((size_t)(bb * NHEAD + hh)) * SS * HDIM + (size_t)s0 * HDIM + d;
#pragma unroll
        for (int r = 0; r < 4; r++)
          outp[base + (size_t)r * HDIM] = f2bs(acc[i][j][r] + bvv);
      }
    } else {
#pragma unroll
      for (int i = 0; i < 4; i++) {
        const int row0 = m0 + wm + i * 16 + quad * 4;
        const int bb = row0 >> 11, s0 = row0 & 2047;
        ushort4 pk;
        pk.x = f2bs(acc[i][j][0] + bvv);
        pk.y = f2bs(acc[i][j][1] + bvv);
        pk.z = f2bs(acc[i][j][2] + bvv);
        pk.w = f2bs(acc[i][j][3] + bvv);
        *(ushort4*)&vth[((size_t)(bb * NHEAD + hh)) * HDIM * SS + (size_t)d * SS + s0] = pk;
      }
    }
  }
}

// ===================== out-proj GEMM (bf16 A/W, fp32 out) =====================
__global__ __launch_bounds__(256) void out_gemm(const unsigned short* __restrict__ A,
                                                const unsigned short* __restrict__ W,
                                                const float* __restrict__ bias,
                                                float* __restrict__ C) {
  __shared__ unsigned short As[128 * 32];
  __shared__ unsigned short Bs[128 * 32];
  const int bid = blockIdx.x;
  const int mt = bid >> 3, nt = bid & 7;
  const int m0 = mt << 7, n0 = nt << 7;
  const int tid = threadIdx.x;
  const int lane = tid & 63, wave = tid >> 6;
  const int quad = lane >> 4, l15 = lane & 15;
  const int wm = ((wave >> 1) << 6), wn = ((wave & 1) << 6);

  const int c0 = wave * 128 + lane;
  const int c1 = c0 + 64;
  const unsigned short* gA0 = A + (size_t)(m0 + (c0 >> 2)) * HID + (c0 & 3) * 8;
  const unsigned short* gA1 = A + (size_t)(m0 + (c1 >> 2)) * HID + (c1 & 3) * 8;
  const unsigned short* gB0 = W + (size_t)(n0 + (c0 >> 2)) * HID + (c0 & 3) * 8;
  const unsigned short* gB1 = W + (size_t)(n0 + (c1 >> 2)) * HID + (c1 & 3) * 8;
  unsigned short* lA0 = As + (size_t)(wave * 128) * 8;
  unsigned short* lA1 = lA0 + 64 * 8;
  unsigned short* lB0 = Bs + (size_t)(wave * 128) * 8;
  unsigned short* lB1 = lB0 + 64 * 8;

  f32x4 acc[4][4] = {};

  for (int k0 = 0; k0 < HID; k0 += 32) {
    __syncthreads();
    gload16(gA0 + k0, lA0);
    gload16(gA1 + k0, lA1);
    gload16(gB0 + k0, lB0);
    gload16(gB1 + k0, lB1);
    __syncthreads();
    bf16x8 af[4], bfr[4];
#pragma unroll
    for (int i = 0; i < 4; i++)
      af[i] = *(const bf16x8*)(As + (wm + i * 16 + l15) * 32 + quad * 8);
#pragma unroll
    for (int j = 0; j < 4; j++)
      bfr[j] = *(const bf16x8*)(Bs + (wn + j * 16 + l15) * 32 + quad * 8);
#pragma unroll
    for (int i = 0; i < 4; i++)
#pragma unroll
      for (int j = 0; j < 4; j++)
        acc[i][j] = __builtin_amdgcn_mfma_f32_16x16x32_bf16(af[i], bfr[j], acc[i][j], 0, 0, 0);
  }

#pragma unroll
  for (int j = 0; j < 4; j++) {
    const int col = n0 + wn + j * 16 + l15;
    const float bvv = bias[col];
#pragma unroll
    for (int i = 0; i < 4; i++) {
      const int row0 = m0 + wm + i * 16 + quad * 4;
#pragma unroll
      for (int r = 0; r < 4; r++)
        C[(size_t)(row0 + r) * HID + col] = acc[i][j][r] + bvv;
    }
  }
}

// ===================== legacy fp32-staging GEMM (fallback plan) =====================
__device__ __forceinline__ void stage_tile(unsigned short* s, const float* g, int ldg, int tid) {
#pragma unroll
  for (int i = 0; i < 4; i++) {
    int c = i * 256 + tid;
    int row = c >> 3;
    int col = (c & 7) * 4;
    const float4 v = *(const float4*)(g + (size_t)row * ldg + col);
    ushort4 hv;
    hv.x = f2bs(v.x); hv.y = f2bs(v.y); hv.z = f2bs(v.z); hv.w = f2bs(v.w);
    *(ushort4*)(s + c * 4) = hv;
  }
}
__device__ __forceinline__ void stage_tile(unsigned short* s, const unsigned short* g, int ldg, int tid) {
#pragma unroll
  for (int i = 0; i < 2; i++) {
    int c = i * 256 + tid;
    int row = c >> 2;
    int col = (c & 3) * 8;
    const uint4 v = *(const uint4*)(g + (size_t)row * ldg + col);
    *(uint4*)(s + c * 8) = v;
  }
}

template <typename TA, int MODE>
__global__ __launch_bounds__(256) void gemm_bt(const TA* __restrict__ A, const float* __restrict__ W,
                                               const float* __restrict__ bias, void* __restrict__ Cp,
                                               int M, int N, int K) {
  __shared__ unsigned short As[128 * 32];
  __shared__ unsigned short Bs[128 * 32];
  const int nb = N >> 7;
  const int m0 = (blockIdx.x / nb) << 7;
  const int n0 = (blockIdx.x % nb) << 7;
  const int tid = threadIdx.x;
  const int lane = tid & 63, wave = tid >> 6;
  const int quad = lane >> 4, l15 = lane & 15;
  const int wm = ((wave >> 1) << 6), wn = ((wave & 1) << 6);

  f32x4 acc[4][4] = {};

  for (int k0 = 0; k0 < K; k0 += 32) {
    __syncthreads();
    stage_tile(As, A + (size_t)m0 * K + k0, K, tid);
    stage_tile(Bs, W + (size_t)n0 * K + k0, K, tid);
    __syncthreads();
    bf16x8 af[4], bfr[4];
#pragma unroll
    for (int i = 0; i < 4; i++)
      af[i] = *(const bf16x8*)(As + (wm + i * 16 + l15) * 32 + quad * 8);
#pragma unroll
    for (int j = 0; j < 4; j++)
      bfr[j] = *(const bf16x8*)(Bs + (wn + j * 16 + l15) * 32 + quad * 8);
#pragma unroll
    for (int i = 0; i < 4; i++)
#pragma unroll
      for (int j = 0; j < 4; j++)
        acc[i][j] = __builtin_amdgcn_mfma_f32_16x16x32_bf16(af[i], bfr[j], acc[i][j], 0, 0, 0);
  }

#pragma unroll
  for (int j = 0; j < 4; j++) {
    const int col = n0 + wn + j * 16 + l15;
    const float bvv = bias[col];
    if constexpr (MODE == 0) {
      float* outp = (float*)Cp;
#pragma unroll
      for (int i = 0; i < 4; i++) {
        const int row0 = m0 + wm + i * 16 + quad * 4;
#pragma unroll
        for (int r = 0; r < 4; r++)
          outp[(size_t)(row0 + r) * N + col] = acc[i][j][r] + bvv;
      }
    } else if constexpr (MODE == 1) {
      unsigned short* outp = (unsigned short*)Cp;
      const int hh = col >> 6, d = col & 63;
#pragma unroll
      for (int i = 0; i < 4; i++) {
        const int row0 = m0 + wm + i * 16 + quad * 4;
        const int bb = row0 >> 11, s0 = row0 & 2047;
        const size_t base = ((size_t)(bb * NHEAD + hh)) * SS * HDIM + (size_t)s0 * HDIM + d;
#pragma unroll
        for (int r = 0; r < 4; r++)
          outp[base + (size_t)r * HDIM] = f2bs(acc[i][j][r] + bvv);
      }
    } else {
      unsigned short* outp = (unsigned short*)Cp;
      const int hh = col >> 6, d = col & 63;
#pragma unroll
      for (int i = 0; i < 4; i++) {
        const int row0 = m0 + wm + i * 16 + quad * 4;
        const int bb = row0 >> 11, s0 = row0 & 2047;
        ushort4 pk;
        pk.x = f2bs(acc[i][j][0] + bvv);
        pk.y = f2bs(acc[i][j][1] + bvv);
        pk.z = f2bs(acc[i][j][2] + bvv);
        pk.w = f2bs(acc[i][j][3] + bvv);
        *(ushort4*)&outp[((size_t)(bb * NHEAD + hh)) * HDIM * SS + (size_t)d * SS + s0] = pk;
      }
    }
  }
}

// ===================== flash attention (unchanged from round 2) =====================
#define KSTR 72
#define VSTR 136
#define PSTR 136

__global__ __launch_bounds__(256) void attn_v2(const unsigned short* __restrict__ q,
                                               const unsigned short* __restrict__ k,
                                               const unsigned short* __restrict__ vt,
                                               const float* __restrict__ mask,
                                               unsigned short* __restrict__ ctx) {
  __shared__ unsigned short Ks[128 * KSTR];
  __shared__ unsigned short Vts[64 * VSTR];
  __shared__ unsigned short Ps[4 * 16 * PSTR];
  __shared__ float Ms[128];

  const int bid = blockIdx.x;
  const int qt = bid & 31;
  const int h  = (bid >> 5) & 15;
  const int b  = bid >> 9;
  const int bh = b * NHEAD + h;
  const int tid = threadIdx.x;
  const int wave = tid >> 6, lane = tid & 63;
  const int quad = lane >> 4, l15 = lane & 15;
  const int q0 = qt * 64 + wave * 16;

  const unsigned short* qbase = q + ((size_t)bh * SS + q0 + l15) * HDIM;
  bf16x8 qf[2];
  qf[0] = *(const bf16x8*)(qbase + quad * 8);
  qf[1] = *(const bf16x8*)(qbase + 32 + quad * 8);

  f32x4 O[4] = {};
  float mrun = -1e30f, lrun = 0.0f;

  const unsigned short* kg0 = k + (size_t)bh * SS * HDIM;
  const unsigned short* vg0 = vt + (size_t)bh * HDIM * SS;
  unsigned short* pw = &Ps[wave * 16 * PSTR];

  for (int kb = 0; kb < SS / 128; kb++) {
    __syncthreads();
    {
      const unsigned short* kg = kg0 + (size_t)kb * 128 * HDIM;
#pragma unroll
      for (int i = 0; i < 4; i++) {
        int c = i * 256 + tid;
        uint4 vv = *(const uint4*)(kg + c * 8);
        int row = c >> 3, col = (c & 7) * 8;
        *(uint4*)&Ks[row * KSTR + col] = vv;
      }
      const unsigned short* vg = vg0 + (size_t)kb * 128;
#pragma unroll
      for (int i = 0; i < 4; i++) {
        int c = i * 256 + tid;
        int row = c >> 4, col = (c & 15) * 8;
        uint4 vv = *(const uint4*)(vg + (size_t)row * SS + col);
        *(uint4*)&Vts[row * VSTR + col] = vv;
      }
      if (tid < 128) Ms[tid] = (1.0f - mask[b * SS + kb * 128 + tid]) * -10000.0f;
    }
    __syncthreads();

    f32x4 Sc[8];
#pragma unroll
    for (int mt = 0; mt < 8; mt++) {
      f32x4 z = {};
#pragma unroll
      for (int kc = 0; kc < 2; kc++) {
        bf16x8 kf = *(const bf16x8*)&Ks[(mt * 16 + l15) * KSTR + kc * 32 + quad * 8];
        z = __builtin_amdgcn_mfma_f32_16x16x32_bf16(kf, qf[kc], z, 0, 0, 0);
      }
      f32x4 mv = *(const f32x4*)&Ms[mt * 16 + quad * 4];
      Sc[mt] = z * 0.125f + mv;
    }

    float mx = -1e30f;
#pragma unroll
    for (int mt = 0; mt < 8; mt++)
#pragma unroll
      for (int r = 0; r < 4; r++) mx = fmaxf(mx, Sc[mt][r]);
    mx = fmaxf(mx, __shfl_xor(mx, 16));
    mx = fmaxf(mx, __shfl_xor(mx, 32));
    float mnew = fmaxf(mrun, mx);
    float alpha = __expf(mrun - mnew);
    mrun = mnew;
    float rs = 0.0f;
#pragma unroll
    for (int mt = 0; mt < 8; mt++)
#pragma unroll
      for (int r = 0; r < 4; r++) {
        float p = __expf(Sc[mt][r] - mnew);
        Sc[mt][r] = p;
        rs += p;
      }
    rs += __shfl_xor(rs, 16);
    rs += __shfl_xor(rs, 32);
    lrun = lrun * alpha + rs;

    float al[4];
#pragma unroll
    for (int r = 0; r < 4; r++) al[r] = __shfl(alpha, quad * 4 + r);
#pragma unroll
    for (int nt = 0; nt < 4; nt++)
#pragma unroll
      for (int r = 0; r < 4; r++) O[nt][r] *= al[r];

#pragma unroll
    for (int mt = 0; mt < 8; mt++) {
      ushort4 pk;
      pk.x = f2bs(Sc[mt][0]); pk.y = f2bs(Sc[mt][1]);
      pk.z = f2bs(Sc[mt][2]); pk.w = f2bs(Sc[mt][3]);
      *(ushort4*)&pw[l15 * PSTR + mt * 16 + quad * 4] = pk;
    }

#pragma unroll
    for (int kc = 0; kc < 4; kc++) {
      bf16x8 pf = *(const bf16x8*)&pw[l15 * PSTR + kc * 32 + quad * 8];
#pragma unroll
      for (int nt = 0; nt < 4; nt++) {
        bf16x8 vf = *(const bf16x8*)&Vts[(nt * 16 + l15) * VSTR + kc * 32 + quad * 8];
        O[nt] = __builtin_amdgcn_mfma_f32_16x16x32_bf16(pf, vf, O[nt], 0, 0, 0);
      }
    }
  }

  float invl = 1.0f / lrun;
  float lr[4];
#pragma unroll
  for (int r = 0; r < 4; r++) lr[r] = __shfl(invl, quad * 4 + r);
#pragma unroll
  for (int nt = 0; nt < 4; nt++)
#pragma unroll
    for (int r = 0; r < 4; r++)
      ctx[((size_t)(b * SS) + q0 + quad * 4 + r) * HID + h * 64 + nt * 16 + l15] =
          f2bs(O[nt][r] * lr[r]);
}

extern "C" void kernel_launch(void* const* d_in, const int* in_sizes, int n_in,
                              void* d_out, int out_size, void* d_ws, size_t ws_size,
                              hipStream_t stream) {
  const float* query = (const float*)d_in[0];
  const float* key_  = (const float*)d_in[1];
  const float* value = (const float*)d_in[2];
  const float* mask  = (const float*)d_in[3];
  const float* Wq = (const float*)d_in[4];
  const float* bq = (const float*)d_in[5];
  const float* Wk = (const float*)d_in[6];
  const float* bk = (const float*)d_in[7];
  const float* Wv = (const float*)d_in[8];
  const float* bv = (const float*)d_in[9];
  const float* Wo = (const float*)d_in[10];
  const float* bo = (const float*)d_in[11];
  float* out = (float*)d_out;

  const size_t ME = (size_t)MTOK * HID;
  const size_t HH = (size_t)HID * HID;
  const size_t needA = (6 * ME + 4 * HH) * 2;

  dim3 blk(256);

  if (ws_size >= needA) {
    // Plan A: pre-converted bf16 everywhere + global_load_lds GEMMs
    unsigned short* xq   = (unsigned short*)d_ws;
    unsigned short* xk   = xq + ME;
    unsigned short* xv   = xk + ME;
    unsigned short* qhm  = xv + ME;   // [B,NH,S,64]
    unsigned short* khm  = qhm + ME;  // [B,NH,S,64]
    unsigned short* vth  = khm + ME;  // [B,NH,64,S]
    unsigned short* wcat = vth + ME;  // Wq,Wk,Wv bf16
    unsigned short* wobf = wcat + 3 * HH;
    unsigned short* cx   = xq;        // alias: xq dead after qkv_gemm

    cvt_all<<<3584, blk, 0, stream>>>(query, key_, value, Wq, Wk, Wv, Wo,
                                      xq, xk, xv, wcat, wobf);
    qkv_gemm<<<64 * 24, blk, 0, stream>>>(xq, xk, xv, wcat, bq, bk, bv, qhm, khm, vth);
    attn_v2<<<BB * NHEAD * (SS / 64), blk, 0, stream>>>(qhm, khm, vth, mask, cx);
    out_gemm<<<64 * 8, blk, 0, stream>>>(cx, wobf, bo, out);
  } else {
    // Plan C fallback: proven round-2 path (67.1 MB workspace)
    unsigned short* qhm = (unsigned short*)d_ws;
    unsigned short* khm = qhm + ME;
    unsigned short* vth = khm + ME;
    unsigned short* cx  = vth + ME;
    const int gblocks = (MTOK / 128) * (HID / 128);  // 512

    gemm_bt<float, 1><<<gblocks, blk, 0, stream>>>(query, Wq, bq, qhm, MTOK, HID, HID);
    gemm_bt<float, 1><<<gblocks, blk, 0, stream>>>(key_, Wk, bk, khm, MTOK, HID, HID);
    gemm_bt<float, 2><<<gblocks, blk, 0, stream>>>(value, Wv, bv, vth, MTOK, HID, HID);
    attn_v2<<<BB * NHEAD * (SS / 64), blk, 0, stream>>>(qhm, khm, vth, mask, cx);
    gemm_bt<unsigned short, 0><<<gblocks, blk, 0, stream>>>(cx, Wo, bo, out, MTOK, HID, HID);
  }
}